// Round 1
// baseline (260.492 us; speedup 1.0000x reference)
//
#include <hip/hip_runtime.h>
#include <hip/hip_bf16.h>
#include <math.h>

#define B_ 8
#define S_ 4096
#define C_ 64
#define EPSV 1e-5f

using floatx4 = __attribute__((ext_vector_type(4))) float;
using bf16x8  = __attribute__((ext_vector_type(8))) short;
using intx4   = __attribute__((ext_vector_type(4))) int;

__device__ __forceinline__ short f2bf(float f) {
    unsigned u = __builtin_bit_cast(unsigned, f);
    u = u + 0x7fffu + ((u >> 16) & 1u);   // RNE
    return (short)(u >> 16);
}

__device__ __forceinline__ unsigned cvt_pk_bf16(float lo, float hi) {
    unsigned r;
    asm volatile("v_cvt_pk_bf16_f32 %0, %1, %2" : "=v"(r) : "v"(lo), "v"(hi));
    return r;
}

// B-fragment (or Wv A-fragment) from a row-major fp32 64x64 weight matrix:
// lane reads W[16*n + c][32*kk + 8*g .. +8] and converts to bf16.
__device__ __forceinline__ bf16x8 ld_w_frag(const float* __restrict__ W, int n, int kk, int g, int c) {
    const float* p = W + (16 * n + c) * C_ + 32 * kk + 8 * g;
    bf16x8 r;
#pragma unroll
    for (int j = 0; j < 8; ++j) r[j] = f2bf(p[j]);
    return r;
}

// ---------------- kernel 1: per-batch mean / rsqrt(var) ----------------
__global__ __launch_bounds__(1024) void stats_kernel(const float* __restrict__ x,
                                                     float* __restrict__ stats) {
    int b = blockIdx.x;
    const float4* xb = (const float4*)(x + (size_t)b * (S_ * C_));
    float s = 0.f, ss = 0.f;
#pragma unroll 8
    for (int i = 0; i < 64; ++i) {
        float4 v = xb[threadIdx.x + i * 1024];
        s  += v.x + v.y + v.z + v.w;
        ss += v.x * v.x + v.y * v.y + v.z * v.z + v.w * v.w;
    }
    for (int off = 32; off > 0; off >>= 1) {
        s  += __shfl_down(s, off);
        ss += __shfl_down(ss, off);
    }
    __shared__ float sm[16], ssm[16];
    int wid = threadIdx.x >> 6, lane = threadIdx.x & 63;
    if (lane == 0) { sm[wid] = s; ssm[wid] = ss; }
    __syncthreads();
    if (threadIdx.x == 0) {
        float S = 0.f, SS = 0.f;
        for (int i = 0; i < 16; ++i) { S += sm[i]; SS += ssm[i]; }
        const float invN = 1.0f / (float)(S_ * C_);
        float mu  = S * invN;
        float var = SS * invN - mu * mu;
        stats[b * 2]     = mu;
        stats[b * 2 + 1] = rsqrtf(var + EPSV);
    }
}

// ---------------- kernel 2: normalize + Q/K/V^T projections ----------------
__global__ __launch_bounds__(256) void proj_kernel(
    const float* __restrict__ x,
    const float* __restrict__ Wq, const float* __restrict__ bq,
    const float* __restrict__ Wk, const float* __restrict__ bk,
    const float* __restrict__ Wv, const float* __restrict__ bv,
    const float* __restrict__ stats,
    short* __restrict__ qo, short* __restrict__ ko, short* __restrict__ vto) {
    __shared__ char hbuf[64 * 128];  // [64 rows][64 bf16], XOR-swizzled

    int b  = blockIdx.x >> 6;
    int s0 = (blockIdx.x & 63) * 64;
    float mu = stats[b * 2], rs = stats[b * 2 + 1];
    const float* xt = x + ((size_t)b * S_ + s0) * C_;
    int t = threadIdx.x;

#pragma unroll
    for (int i = 0; i < 4; ++i) {
        int fi  = t + 256 * i;       // float4 index within 64x64 tile
        int row = fi >> 4;
        int c4  = fi & 15;
        float4 v = *(const float4*)(xt + row * C_ + c4 * 4);
        unsigned lo = (unsigned)(unsigned short)f2bf((v.x - mu) * rs) |
                      ((unsigned)(unsigned short)f2bf((v.y - mu) * rs) << 16);
        unsigned hi = (unsigned)(unsigned short)f2bf((v.z - mu) * rs) |
                      ((unsigned)(unsigned short)f2bf((v.w - mu) * rs) << 16);
        int off = row * 128 + c4 * 8;
        off ^= (row & 7) << 4;
        *(uint2*)(hbuf + off) = make_uint2(lo, hi);
    }
    __syncthreads();

    int lane = t & 63, w = t >> 6;
    int g = lane >> 4, c = lane & 15;

    auto ld_h = [&](int row, int kcol) -> bf16x8 {
        int off = row * 128 + kcol * 2;
        off ^= (row & 7) << 4;
        return *(const bf16x8*)(hbuf + off);
    };

    // ---- Q and K: D = h @ W^T.  A = h rows 16w..16w+15 ----
    bf16x8 ha[2];
    ha[0] = ld_h(16 * w + c, 8 * g);
    ha[1] = ld_h(16 * w + c, 32 + 8 * g);

    const float QSC = 0.125f * 1.44269504088896340736f;  // C^-0.5 * log2(e)

#pragma unroll
    for (int n = 0; n < 4; ++n) {
        floatx4 aq = {0.f, 0.f, 0.f, 0.f}, ak = {0.f, 0.f, 0.f, 0.f};
#pragma unroll
        for (int kk = 0; kk < 2; ++kk) {
            bf16x8 wq = ld_w_frag(Wq, n, kk, g, c);
            bf16x8 wk = ld_w_frag(Wk, n, kk, g, c);
            aq = __builtin_amdgcn_mfma_f32_16x16x32_bf16(ha[kk], wq, aq, 0, 0, 0);
            ak = __builtin_amdgcn_mfma_f32_16x16x32_bf16(ha[kk], wk, ak, 0, 0, 0);
        }
        float bqv = bq[16 * n + c], bkv = bk[16 * n + c];
#pragma unroll
        for (int r = 0; r < 4; ++r) {
            int srow = s0 + 16 * w + 4 * g + r;
            size_t base = ((size_t)b * S_ + srow) * C_ + 16 * n + c;
            qo[base] = f2bf((aq[r] + bqv) * QSC);
            ko[base] = f2bf(ak[r] + bkv);
        }
    }

    // ---- V^T = Wv @ h^T (direct transposed output). A = Wv rows 16w..16w+15 ----
    bf16x8 wv[2];
    wv[0] = ld_w_frag(Wv, w, 0, g, c);
    wv[1] = ld_w_frag(Wv, w, 1, g, c);
    float bvr[4];
#pragma unroll
    for (int r = 0; r < 4; ++r) bvr[r] = bv[16 * w + 4 * g + r];

#pragma unroll
    for (int n = 0; n < 4; ++n) {
        floatx4 av = {0.f, 0.f, 0.f, 0.f};
#pragma unroll
        for (int kk = 0; kk < 2; ++kk) {
            bf16x8 hb = ld_h(16 * n + c, 32 * kk + 8 * g);
            av = __builtin_amdgcn_mfma_f32_16x16x32_bf16(wv[kk], hb, av, 0, 0, 0);
        }
#pragma unroll
        for (int r = 0; r < 4; ++r) {
            int crow = 16 * w + 4 * g + r;
            vto[((size_t)b * C_ + crow) * S_ + s0 + 16 * n + c] = f2bf(av[r] + bvr[r]);
        }
    }
}

// ---------------- kernel 3: flash attention + Wo + residual ----------------
__global__ __launch_bounds__(256) void flash_kernel(
    const short* __restrict__ qm, const short* __restrict__ km, const short* __restrict__ vt,
    const float* __restrict__ Wo, const float* __restrict__ bo,
    const float* __restrict__ x, float* __restrict__ out) {
    __shared__ char obuf[4][2048];  // per-wave [16 q][64 c] bf16, XOR-swizzled

    int b = blockIdx.x >> 6;
    int t = threadIdx.x;
    int lane = t & 63, w = t >> 6;
    int g = lane >> 4, c = lane & 15;
    int q0 = (blockIdx.x & 63) * 64 + 16 * w;

    const short* qp = qm + (size_t)b * S_ * C_;
    const short* kp = km + (size_t)b * S_ * C_;
    const short* vp = vt + (size_t)b * C_ * S_;

    // Q^T B-fragments (held for whole loop): lane reads q row (q0+c)
    bf16x8 bqf[2];
    bqf[0] = *(const bf16x8*)(qp + (q0 + c) * C_ + 8 * g);
    bqf[1] = *(const bf16x8*)(qp + (q0 + c) * C_ + 32 + 8 * g);

    floatx4 oacc[4];
#pragma unroll
    for (int n = 0; n < 4; ++n) oacc[n] = (floatx4){0.f, 0.f, 0.f, 0.f};
    float m = -__builtin_inff(), lsum = 0.f;

    const int addr0 = ((2 * (g & 1)) * 16 + c) * 4;  // bpermute src lane*4
    const int addr1 = addr0 + 64;
    const bool kbhi = (g >> 1) != 0;

    for (int kv0 = 0; kv0 < S_; kv0 += 32) {
        // ---- S^T tile = K @ Q^T  (swapped so stats are per-lane) ----
        floatx4 st0 = {0.f, 0.f, 0.f, 0.f}, st1 = {0.f, 0.f, 0.f, 0.f};
#pragma unroll
        for (int kk = 0; kk < 2; ++kk) {
            bf16x8 ak0 = *(const bf16x8*)(kp + (kv0 + c) * C_ + 32 * kk + 8 * g);
            bf16x8 ak1 = *(const bf16x8*)(kp + (kv0 + 16 + c) * C_ + 32 * kk + 8 * g);
            st0 = __builtin_amdgcn_mfma_f32_16x16x32_bf16(ak0, bqf[kk], st0, 0, 0, 0);
            st1 = __builtin_amdgcn_mfma_f32_16x16x32_bf16(ak1, bqf[kk], st1, 0, 0, 0);
        }

        // ---- online softmax (q = q0 + c per lane; scores pre-scaled to log2 domain) ----
        float mt = st0[0];
        mt = fmaxf(mt, st0[1]); mt = fmaxf(mt, st0[2]); mt = fmaxf(mt, st0[3]);
        mt = fmaxf(mt, st1[0]); mt = fmaxf(mt, st1[1]);
        mt = fmaxf(mt, st1[2]); mt = fmaxf(mt, st1[3]);
        mt = fmaxf(mt, __shfl_xor(mt, 16));
        mt = fmaxf(mt, __shfl_xor(mt, 32));
        float mnew  = fmaxf(m, mt);
        float alpha = __builtin_amdgcn_exp2f(m - mnew);
        float p0[4], p1[4], psum = 0.f;
#pragma unroll
        for (int r = 0; r < 4; ++r) {
            p0[r] = __builtin_amdgcn_exp2f(st0[r] - mnew);
            p1[r] = __builtin_amdgcn_exp2f(st1[r] - mnew);
            psum += p0[r] + p1[r];
        }
        lsum = lsum * alpha + psum;
        m = mnew;
#pragma unroll
        for (int n = 0; n < 4; ++n) oacc[n] *= alpha;

        // ---- redistribute P^T into PV B-fragment via bpermute ----
        unsigned pk00 = cvt_pk_bf16(p0[0], p0[1]);
        unsigned pk01 = cvt_pk_bf16(p0[2], p0[3]);
        unsigned pk10 = cvt_pk_bf16(p1[0], p1[1]);
        unsigned pk11 = cvt_pk_bf16(p1[2], p1[3]);
        int w0a = __builtin_amdgcn_ds_bpermute(addr0, (int)pk00);
        int w0b = __builtin_amdgcn_ds_bpermute(addr0, (int)pk10);
        int w1a = __builtin_amdgcn_ds_bpermute(addr0, (int)pk01);
        int w1b = __builtin_amdgcn_ds_bpermute(addr0, (int)pk11);
        int w2a = __builtin_amdgcn_ds_bpermute(addr1, (int)pk00);
        int w2b = __builtin_amdgcn_ds_bpermute(addr1, (int)pk10);
        int w3a = __builtin_amdgcn_ds_bpermute(addr1, (int)pk01);
        int w3b = __builtin_amdgcn_ds_bpermute(addr1, (int)pk11);
        intx4 bpw;
        bpw[0] = kbhi ? w0b : w0a;
        bpw[1] = kbhi ? w1b : w1a;
        bpw[2] = kbhi ? w2b : w2a;
        bpw[3] = kbhi ? w3b : w3a;
        bf16x8 bp = __builtin_bit_cast(bf16x8, bpw);

        // ---- O^T += V^T @ P^T ----
#pragma unroll
        for (int mi = 0; mi < 4; ++mi) {
            bf16x8 av = *(const bf16x8*)(vp + (16 * mi + c) * S_ + kv0 + 8 * g);
            oacc[mi] = __builtin_amdgcn_mfma_f32_16x16x32_bf16(av, bp, oacc[mi], 0, 0, 0);
        }
    }

    // ---- finalize: l reduce, normalize, transpose O via LDS ----
    lsum += __shfl_xor(lsum, 16);
    lsum += __shfl_xor(lsum, 32);
    float inv = 1.0f / lsum;

    char* ob = obuf[w];
#pragma unroll
    for (int mi = 0; mi < 4; ++mi) {
#pragma unroll
        for (int h = 0; h < 2; ++h) {
            unsigned pkv = cvt_pk_bf16(oacc[mi][2 * h] * inv, oacc[mi][2 * h + 1] * inv);
            int off = c * 128 + (16 * mi + 4 * g) * 2 + 4 * h;
            off ^= (c & 7) << 4;
            *(unsigned*)(ob + off) = pkv;
        }
    }
    __syncthreads();

    bf16x8 ao[2];
    {
        int off0 = c * 128 + (8 * g) * 2;        off0 ^= (c & 7) << 4;
        int off1 = c * 128 + (32 + 8 * g) * 2;   off1 ^= (c & 7) << 4;
        ao[0] = *(const bf16x8*)(ob + off0);
        ao[1] = *(const bf16x8*)(ob + off1);
    }

    // out = o @ Wo^T + bo + x
#pragma unroll
    for (int n = 0; n < 4; ++n) {
        floatx4 a = {0.f, 0.f, 0.f, 0.f};
#pragma unroll
        for (int kk = 0; kk < 2; ++kk) {
            bf16x8 bw = ld_w_frag(Wo, n, kk, g, c);
            a = __builtin_amdgcn_mfma_f32_16x16x32_bf16(ao[kk], bw, a, 0, 0, 0);
        }
        float bov = bo[16 * n + c];
#pragma unroll
        for (int r = 0; r < 4; ++r) {
            int srow = q0 + 4 * g + r;
            size_t idx = ((size_t)b * S_ + srow) * C_ + 16 * n + c;
            out[idx] = x[idx] + bov + a[r];
        }
    }
}

extern "C" void kernel_launch(void* const* d_in, const int* in_sizes, int n_in,
                              void* d_out, int out_size, void* d_ws, size_t ws_size,
                              hipStream_t stream) {
    const float* x  = (const float*)d_in[0];
    // d_in[1] = temb (unused by reference)
    const float* Wq = (const float*)d_in[2];
    const float* bq = (const float*)d_in[3];
    const float* Wk = (const float*)d_in[4];
    const float* bk = (const float*)d_in[5];
    const float* Wv = (const float*)d_in[6];
    const float* bv = (const float*)d_in[7];
    const float* Wo = (const float*)d_in[8];
    const float* bo = (const float*)d_in[9];
    float* out = (float*)d_out;

    char* ws = (char*)d_ws;
    float* stats = (float*)ws;                      // 16 floats
    short* q  = (short*)(ws + 256);                 // [B][S][C] bf16
    short* k  = q + (size_t)B_ * S_ * C_;           // [B][S][C] bf16
    short* vt = k + (size_t)B_ * S_ * C_;           // [B][C][S] bf16

    stats_kernel<<<B_, 1024, 0, stream>>>(x, stats);
    proj_kernel<<<B_ * (S_ / 64), 256, 0, stream>>>(x, Wq, bq, Wk, bk, Wv, bv, stats, q, k, vt);
    flash_kernel<<<B_ * (S_ / 64), 256, 0, stream>>>(q, k, vt, Wo, bo, x, out);
}